// Round 18
// baseline (388.321 us; speedup 1.0000x reference)
//
#include <hip/hip_runtime.h>
#include <math.h>

typedef unsigned int u32;
typedef unsigned long long u64;
typedef float f32x4 __attribute__((ext_vector_type(4)));

#define NBKT 65536   // 16-bit prefix buckets
#define RANK_CAP 32768

// ===== Bit-exact replica of XLA's f32 tanh =====
__device__ __forceinline__ float xla_tanhf(float x) {
    float xc = fminf(fmaxf(x, -9.0f), 9.0f);
    float x2 = __fmul_rn(xc, xc);
    float p = -2.76076847742355e-16f;
    p = __fadd_rn(__fmul_rn(p, x2),  2.00018790482477e-13f);
    p = __fadd_rn(__fmul_rn(p, x2), -8.60467152213735e-11f);
    p = __fadd_rn(__fmul_rn(p, x2),  5.12229709037114e-08f);
    p = __fadd_rn(__fmul_rn(p, x2),  1.48572235717979e-05f);
    p = __fadd_rn(__fmul_rn(p, x2),  6.37261928875436e-04f);
    p = __fadd_rn(__fmul_rn(p, x2),  4.89352455891786e-03f);
    p = __fmul_rn(xc, p);
    float q = 1.19825839466702e-06f;
    q = __fadd_rn(__fmul_rn(q, x2),  1.18534705686654e-04f);
    q = __fadd_rn(__fmul_rn(q, x2),  2.26843463243900e-03f);
    q = __fadd_rn(__fmul_rn(q, x2),  4.89352518554385e-03f);
    float r = p / q;                     // IEEE f32 divide
    return (fabsf(x) < 0.0004f) ? x : r;
}

__device__ __forceinline__ u32 key_desc(float f) {
    u32 u = __float_as_uint(f);
    u = (u & 0x80000000u) ? ~u : (u | 0x80000000u);
    return ~u;
}

// tanh table + cluster init + bucket histogram + int64/int32 layout detect
__global__ void k_prep(const float* __restrict__ score, float* __restrict__ s,
                       int* __restrict__ cluster, u32* __restrict__ hist,
                       const int* __restrict__ ei, const int* __restrict__ ntype,
                       u32* __restrict__ flags, int N) {
    int i = blockIdx.x * blockDim.x + threadIdx.x;
    if (i < 2048) { if (ei[2 * i + 1] != 0) atomicOr(&flags[0], 1u); }
    else if (i < 4096) { int j = i - 2048; if (ntype[2 * j + 1] != 0) atomicOr(&flags[1], 1u); }
    if (i < N) {
        float t = xla_tanhf(score[i]);
        s[i] = t;
        cluster[i] = -1;
        atomicAdd(&hist[key_desc(t) >> 16], 1u);
    }
}

// MERGED scan: block b derives base = sum(hist[0..256b)) itself (strided),
// then chunk-scans its 256 buckets; writes scan[] AND cursor[].
__global__ void k_scanAB(const u32* __restrict__ hist, u32* __restrict__ scan,
                         u32* __restrict__ cursor) {
    __shared__ u32 sh[256];
    __shared__ u32 base_sh;
    int b = blockIdx.x, t = threadIdx.x;
    u32 acc = 0;
    for (int j = t; j < 256 * b; j += 256) acc += hist[j];
    sh[t] = acc;
    __syncthreads();
    for (int off = 128; off > 0; off >>= 1) {
        if (t < off) sh[t] += sh[t + off];
        __syncthreads();
    }
    if (t == 0) base_sh = sh[0];
    __syncthreads();
    u32 base = base_sh;
    u32 v = hist[b * 256 + t];
    sh[t] = v;
    __syncthreads();
    for (int off = 1; off < 256; off <<= 1) {
        u32 x = sh[t];
        u32 y = (t >= off) ? sh[t - off] : 0u;
        __syncthreads();
        sh[t] = x + y;
        __syncthreads();
    }
    u32 ex = base + sh[t] - v;           // exclusive prefix
    scan[b * 256 + t] = ex;
    cursor[b * 256 + t] = ex;
    if (b == 255 && t == 255) scan[NBKT] = ex + v;   // total = N
}

// scatter packed (key<<32|idx); cursor already holds the bucket base
__global__ void k_scat(const float* __restrict__ s, u32* __restrict__ cursor,
                       u64* __restrict__ pack, int N) {
    int i = blockIdx.x * blockDim.x + threadIdx.x;
    if (i < N) {
        u32 kk = key_desc(s[i]);
        u32 pos = atomicAdd(&cursor[kk >> 16], 1u);
        if (pos < (u32)N) pack[pos] = ((u64)kk << 32) | (u32)i;
    }
}

// exact in-bucket rank (single u64 compare) + fused perm outputs
__global__ void k_rankperm(const u32* __restrict__ scan, const u64* __restrict__ pack,
                           u32* __restrict__ pay, const float* __restrict__ s,
                           const int* __restrict__ ntype, const u32* __restrict__ ntFlag,
                           int* __restrict__ cluster,
                           float* __restrict__ o_nt, float* __restrict__ o_perm,
                           float* __restrict__ o_vals, int k, int N) {
    int i = blockIdx.x * blockDim.x + threadIdx.x;
    if (i < N) {
        u64 pk = pack[i];
        u32 b = (u32)(pk >> 48);
        u32 lo = scan[b], hi = scan[b + 1];
        if (hi > (u32)N) hi = (u32)N;
        if (hi > lo + RANK_CAP) hi = lo + RANK_CAP;
        u32 r = lo;
        for (u32 q = lo; q < hi; ++q) r += (pack[q] < pk);
        if (r < (u32)k) {
            u32 ip = (u32)pk;
            if (ip >= (u32)N) ip = 0;      // defensive
            pay[r] = ip;
            cluster[ip] = (int)r;
            o_perm[r] = (float)ip;
            o_vals[r] = s[ip];
            int nt = (*ntFlag == 0u) ? ntype[2 * (size_t)ip] : ntype[ip];
            o_nt[r] = (float)nt;
        }
    }
}

// x-gather (proven: regular loads, NT store)
__global__ void k_gx(const u32* __restrict__ pay, const float* __restrict__ s,
                     const f32x4* __restrict__ x4, f32x4* __restrict__ out4,
                     int k, int Dv, int N) {
    int idx = blockIdx.x * blockDim.x + threadIdx.x;
    if (idx < k * Dv) {
        int r = idx / Dv, c = idx - r * Dv;
        u32 p = pay[r];
        if (p >= (u32)N) p = 0;
        float v = s[p];
        f32x4 a = x4[(size_t)p * Dv + c];
        a = a * v;
        __builtin_nontemporal_store(a, out4 + idx);
    }
}

// WAVE-chunked fused edges+attr (R16-proven)
__global__ void k_ea(const int* __restrict__ ei, const u32* __restrict__ eiFlag,
                     const float* __restrict__ elen, const int* __restrict__ cluster,
                     const f32x4* __restrict__ attr4,
                     float* __restrict__ o_ei, float* __restrict__ o_len,
                     float* __restrict__ o_mask, f32x4* __restrict__ o_attr4,
                     int E, int N) {
    const bool w64 = (*eiFlag == 0u);
    const int lane = threadIdx.x & 63;
    const int waveId = (blockIdx.x * blockDim.x + threadIdx.x) >> 6;
    const int nWaves = (gridDim.x * blockDim.x) >> 6;
    const int nChunk = (E + 63) >> 6;
    for (int ch = waveId; ch < nChunk; ch += nWaves) {
        int e = ch * 64 + lane;
        int mfl = 0;
        if (e < E) {
            int a, b;
            if (w64) { a = ei[2 * (size_t)e]; b = ei[2 * ((size_t)E + (size_t)e)]; }
            else { a = ei[e]; b = ei[(size_t)E + e]; }
            bool ok = ((u32)a < (u32)N) && ((u32)b < (u32)N);
            int r  = ok ? cluster[a] : -1;
            int cc = ok ? cluster[b] : -1;
            bool m = (r >= 0) && (cc >= 0);
            mfl = m ? 1 : 0;
            __builtin_nontemporal_store(m ? (float)r  : 0.0f, o_ei + e);
            __builtin_nontemporal_store(m ? (float)cc : 0.0f, o_ei + (size_t)E + e);
            __builtin_nontemporal_store(m ? elen[e] : 0.0f, o_len + e);
            __builtin_nontemporal_store(m ? 1.0f : 0.0f, o_mask + e);
        }
        long long base4 = (long long)ch * 256;
        #pragma unroll
        for (int j = 0; j < 4; ++j) {
            long long idx4 = base4 + j * 64 + lane;
            int owner = j * 16 + (lane >> 2);
            int m = __shfl(mfl, owner);
            int ee = ch * 64 + owner;
            if (ee < E) {
                f32x4 v = {0.f, 0.f, 0.f, 0.f};
                if (m) v = attr4[idx4];
                __builtin_nontemporal_store(v, o_attr4 + idx4);
            }
        }
    }
}

extern "C" void kernel_launch(void* const* d_in, const int* in_sizes, int n_in,
                              void* d_out, int out_size, void* d_ws, size_t ws_size,
                              hipStream_t stream) {
    const float* x     = (const float*)d_in[0];
    const float* score = (const float*)d_in[1];
    const int*   ei    = (const int*)d_in[2];
    const float* eattr = (const float*)d_in[3];
    const int*   ntype = (const int*)d_in[4];
    const float* elen  = (const float*)d_in[5];

    const int N  = in_sizes[1];
    const int D  = in_sizes[0] / N;
    const int E  = in_sizes[5];
    const int DE = in_sizes[3] / E;
    const int k  = (N + 1) / 2;     // ceil(0.5 * N)

    // d_out is FLOAT32. RETURN-ORDER layout:
    // x_p | edge_index | edge_attr_p | node_type | perm | vals | edge_lengths | edge_mask
    float* out = (float*)d_out;
    const size_t o_xp    = 0;
    const size_t o_ei    = o_xp    + (size_t)k * D;
    const size_t o_eattr = o_ei    + 2 * (size_t)E;
    const size_t o_nt    = o_eattr + (size_t)E * DE;
    const size_t o_perm  = o_nt    + (size_t)k;
    const size_t o_vals  = o_perm  + (size_t)k;
    const size_t o_elen  = o_vals  + (size_t)k;
    const size_t o_emask = o_elen  + (size_t)E;

    char* ws = (char*)d_ws;
    u64* pack    = (u64*)ws;     ws += 8 * (size_t)N;       // 8B-aligned first
    float* s     = (float*)ws;   ws += 4 * (size_t)N;
    u32* hist    = (u32*)ws;     ws += 4 * (size_t)NBKT;
    u32* flags   = (u32*)ws;     ws += 4 * 2;               // contiguous with hist
    u32* scan    = (u32*)ws;     ws += 4 * ((size_t)NBKT + 2);
    u32* cursor  = (u32*)ws;     ws += 4 * (size_t)NBKT;    // init'd by k_scanAB
    u32* pay     = (u32*)ws;     ws += 4 * (size_t)N;
    int* cluster = (int*)ws;     ws += 4 * (size_t)N;

    const int nbN = (N + 255) / 256;
    // ===== FRONT-END ×2 (MEASUREMENT PROBE; block is idempotent) =====
    // dur_us delta vs a single-pass build == FE cost + gaps.
    for (int rep = 0; rep < 2; ++rep) {
        hipMemsetAsync(hist, 0, sizeof(u32) * (NBKT + 2), stream);   // hist + flags
        k_prep<<<nbN, 256, 0, stream>>>(score, s, cluster, hist, ei, ntype, flags, N);
        k_scanAB<<<256, 256, 0, stream>>>(hist, scan, cursor);
        k_scat<<<nbN, 256, 0, stream>>>(s, cursor, pack, N);
        k_rankperm<<<nbN, 256, 0, stream>>>(scan, pack, pay, s, ntype, &flags[1], cluster,
                                            out + o_nt, out + o_perm, out + o_vals, k, N);
    }
    const int Dv = D / 4;
    const int gx = k * Dv;
    k_gx<<<(gx + 255) / 256, 256, 0, stream>>>(pay, s, (const f32x4*)x,
                                               (f32x4*)(out + o_xp), k, Dv, N);
    k_ea<<<2048, 256, 0, stream>>>(ei, &flags[0], elen, cluster,
                                   (const f32x4*)eattr,
                                   out + o_ei, out + o_elen, out + o_emask,
                                   (f32x4*)(out + o_eattr), E, N);
}

// Round 19
// 309.129 us; speedup vs baseline: 1.2562x; 1.2562x over previous
//
#include <hip/hip_runtime.h>
#include <math.h>

typedef unsigned int u32;
typedef unsigned long long u64;
typedef float f32x4 __attribute__((ext_vector_type(4)));

#define NBKT 65536   // 16-bit prefix buckets
#define RANK_CAP 32768

// ===== Bit-exact replica of XLA's f32 tanh =====
__device__ __forceinline__ float xla_tanhf(float x) {
    float xc = fminf(fmaxf(x, -9.0f), 9.0f);
    float x2 = __fmul_rn(xc, xc);
    float p = -2.76076847742355e-16f;
    p = __fadd_rn(__fmul_rn(p, x2),  2.00018790482477e-13f);
    p = __fadd_rn(__fmul_rn(p, x2), -8.60467152213735e-11f);
    p = __fadd_rn(__fmul_rn(p, x2),  5.12229709037114e-08f);
    p = __fadd_rn(__fmul_rn(p, x2),  1.48572235717979e-05f);
    p = __fadd_rn(__fmul_rn(p, x2),  6.37261928875436e-04f);
    p = __fadd_rn(__fmul_rn(p, x2),  4.89352455891786e-03f);
    p = __fmul_rn(xc, p);
    float q = 1.19825839466702e-06f;
    q = __fadd_rn(__fmul_rn(q, x2),  1.18534705686654e-04f);
    q = __fadd_rn(__fmul_rn(q, x2),  2.26843463243900e-03f);
    q = __fadd_rn(__fmul_rn(q, x2),  4.89352518554385e-03f);
    float r = p / q;                     // IEEE f32 divide
    return (fabsf(x) < 0.0004f) ? x : r;
}

__device__ __forceinline__ u32 key_desc(float f) {
    u32 u = __float_as_uint(f);
    u = (u & 0x80000000u) ? ~u : (u | 0x80000000u);
    return ~u;
}

// tanh table + cluster init + bucket histogram + int64/int32 layout detect
__global__ void k_prep(const float* __restrict__ score, float* __restrict__ s,
                       int* __restrict__ cluster, u32* __restrict__ hist,
                       const int* __restrict__ ei, const int* __restrict__ ntype,
                       u32* __restrict__ flags, int N) {
    int i = blockIdx.x * blockDim.x + threadIdx.x;
    if (i < 2048) { if (ei[2 * i + 1] != 0) atomicOr(&flags[0], 1u); }
    else if (i < 4096) { int j = i - 2048; if (ntype[2 * j + 1] != 0) atomicOr(&flags[1], 1u); }
    if (i < N) {
        float t = xla_tanhf(score[i]);
        s[i] = t;
        cluster[i] = -1;
        atomicAdd(&hist[key_desc(t) >> 16], 1u);
    }
}

// 256 blocks: block b reduces hist[b*256 .. +255] -> part[b]   (R16-proven)
__global__ void k_scanA(const u32* __restrict__ hist, u32* __restrict__ part) {
    __shared__ u32 sh[256];
    int b = blockIdx.x, t = threadIdx.x;
    sh[t] = hist[b * 256 + t];
    __syncthreads();
    for (int off = 128; off > 0; off >>= 1) {
        if (t < off) sh[t] += sh[t + off];
        __syncthreads();
    }
    if (t == 0) part[b] = sh[0];
}

// 256 blocks: base = sum(part[0..b)), chunk-scan, write scan[] AND cursor[]  (R16-proven)
__global__ void k_scanB(const u32* __restrict__ hist, const u32* __restrict__ part,
                        u32* __restrict__ scan, u32* __restrict__ cursor) {
    __shared__ u32 sh[256];
    __shared__ u32 base_sh;
    int b = blockIdx.x, t = threadIdx.x;
    u32 acc = (t < b) ? part[t] : 0u;
    sh[t] = acc;
    __syncthreads();
    for (int off = 128; off > 0; off >>= 1) {
        if (t < off) sh[t] += sh[t + off];
        __syncthreads();
    }
    if (t == 0) base_sh = sh[0];
    __syncthreads();
    u32 base = base_sh;
    u32 v = hist[b * 256 + t];
    sh[t] = v;
    __syncthreads();
    for (int off = 1; off < 256; off <<= 1) {
        u32 x = sh[t];
        u32 y = (t >= off) ? sh[t - off] : 0u;
        __syncthreads();
        sh[t] = x + y;
        __syncthreads();
    }
    u32 ex = base + sh[t] - v;           // exclusive prefix
    scan[b * 256 + t] = ex;
    cursor[b * 256 + t] = ex;
    if (b == 255 && t == 255) scan[NBKT] = ex + v;   // total = N
}

// scatter packed (key<<32|idx); cursor already holds the bucket base
__global__ void k_scat(const float* __restrict__ s, u32* __restrict__ cursor,
                       u64* __restrict__ pack, int N) {
    int i = blockIdx.x * blockDim.x + threadIdx.x;
    if (i < N) {
        u32 kk = key_desc(s[i]);
        u32 pos = atomicAdd(&cursor[kk >> 16], 1u);
        if (pos < (u32)N) pack[pos] = ((u64)kk << 32) | (u32)i;
    }
}

// exact in-bucket rank (single u64 compare) + fused perm outputs
__global__ void k_rankperm(const u32* __restrict__ scan, const u64* __restrict__ pack,
                           u32* __restrict__ pay, const float* __restrict__ s,
                           const int* __restrict__ ntype, const u32* __restrict__ ntFlag,
                           int* __restrict__ cluster,
                           float* __restrict__ o_nt, float* __restrict__ o_perm,
                           float* __restrict__ o_vals, int k, int N) {
    int i = blockIdx.x * blockDim.x + threadIdx.x;
    if (i < N) {
        u64 pk = pack[i];
        u32 b = (u32)(pk >> 48);
        u32 lo = scan[b], hi = scan[b + 1];
        if (hi > (u32)N) hi = (u32)N;
        if (hi > lo + RANK_CAP) hi = lo + RANK_CAP;
        u32 r = lo;
        for (u32 q = lo; q < hi; ++q) r += (pack[q] < pk);
        if (r < (u32)k) {
            u32 ip = (u32)pk;
            if (ip >= (u32)N) ip = 0;      // defensive
            pay[r] = ip;
            cluster[ip] = (int)r;
            o_perm[r] = (float)ip;
            o_vals[r] = s[ip];
            int nt = (*ntFlag == 0u) ? ntype[2 * (size_t)ip] : ntype[ip];
            o_nt[r] = (float)nt;
        }
    }
}

// x-gather (proven: regular loads, NT store)
__global__ void k_gx(const u32* __restrict__ pay, const float* __restrict__ s,
                     const f32x4* __restrict__ x4, f32x4* __restrict__ out4,
                     int k, int Dv, int N) {
    int idx = blockIdx.x * blockDim.x + threadIdx.x;
    if (idx < k * Dv) {
        int r = idx / Dv, c = idx - r * Dv;
        u32 p = pay[r];
        if (p >= (u32)N) p = 0;
        float v = s[p];
        f32x4 a = x4[(size_t)p * Dv + c];
        a = a * v;
        __builtin_nontemporal_store(a, out4 + idx);
    }
}

// WAVE-chunked fused edges+attr (R16-proven)
__global__ void k_ea(const int* __restrict__ ei, const u32* __restrict__ eiFlag,
                     const float* __restrict__ elen, const int* __restrict__ cluster,
                     const f32x4* __restrict__ attr4,
                     float* __restrict__ o_ei, float* __restrict__ o_len,
                     float* __restrict__ o_mask, f32x4* __restrict__ o_attr4,
                     int E, int N) {
    const bool w64 = (*eiFlag == 0u);
    const int lane = threadIdx.x & 63;
    const int waveId = (blockIdx.x * blockDim.x + threadIdx.x) >> 6;
    const int nWaves = (gridDim.x * blockDim.x) >> 6;
    const int nChunk = (E + 63) >> 6;
    for (int ch = waveId; ch < nChunk; ch += nWaves) {
        int e = ch * 64 + lane;
        int mfl = 0;
        if (e < E) {
            int a, b;
            if (w64) { a = ei[2 * (size_t)e]; b = ei[2 * ((size_t)E + (size_t)e)]; }
            else { a = ei[e]; b = ei[(size_t)E + e]; }
            bool ok = ((u32)a < (u32)N) && ((u32)b < (u32)N);
            int r  = ok ? cluster[a] : -1;
            int cc = ok ? cluster[b] : -1;
            bool m = (r >= 0) && (cc >= 0);
            mfl = m ? 1 : 0;
            __builtin_nontemporal_store(m ? (float)r  : 0.0f, o_ei + e);
            __builtin_nontemporal_store(m ? (float)cc : 0.0f, o_ei + (size_t)E + e);
            __builtin_nontemporal_store(m ? elen[e] : 0.0f, o_len + e);
            __builtin_nontemporal_store(m ? 1.0f : 0.0f, o_mask + e);
        }
        long long base4 = (long long)ch * 256;
        #pragma unroll
        for (int j = 0; j < 4; ++j) {
            long long idx4 = base4 + j * 64 + lane;
            int owner = j * 16 + (lane >> 2);
            int m = __shfl(mfl, owner);
            int ee = ch * 64 + owner;
            if (ee < E) {
                f32x4 v = {0.f, 0.f, 0.f, 0.f};
                if (m) v = attr4[idx4];
                __builtin_nontemporal_store(v, o_attr4 + idx4);
            }
        }
    }
}

extern "C" void kernel_launch(void* const* d_in, const int* in_sizes, int n_in,
                              void* d_out, int out_size, void* d_ws, size_t ws_size,
                              hipStream_t stream) {
    const float* x     = (const float*)d_in[0];
    const float* score = (const float*)d_in[1];
    const int*   ei    = (const int*)d_in[2];
    const float* eattr = (const float*)d_in[3];
    const int*   ntype = (const int*)d_in[4];
    const float* elen  = (const float*)d_in[5];

    const int N  = in_sizes[1];
    const int D  = in_sizes[0] / N;
    const int E  = in_sizes[5];
    const int DE = in_sizes[3] / E;
    const int k  = (N + 1) / 2;     // ceil(0.5 * N)

    // d_out is FLOAT32. RETURN-ORDER layout:
    // x_p | edge_index | edge_attr_p | node_type | perm | vals | edge_lengths | edge_mask
    float* out = (float*)d_out;
    const size_t o_xp    = 0;
    const size_t o_ei    = o_xp    + (size_t)k * D;
    const size_t o_eattr = o_ei    + 2 * (size_t)E;
    const size_t o_nt    = o_eattr + (size_t)E * DE;
    const size_t o_perm  = o_nt    + (size_t)k;
    const size_t o_vals  = o_perm  + (size_t)k;
    const size_t o_elen  = o_vals  + (size_t)k;
    const size_t o_emask = o_elen  + (size_t)E;

    char* ws = (char*)d_ws;
    u64* pack    = (u64*)ws;     ws += 8 * (size_t)N;       // 8B-aligned first
    float* s     = (float*)ws;   ws += 4 * (size_t)N;
    u32* hist    = (u32*)ws;     ws += 4 * (size_t)NBKT;
    u32* flags   = (u32*)ws;     ws += 4 * 2;               // contiguous with hist
    u32* scan    = (u32*)ws;     ws += 4 * ((size_t)NBKT + 2);
    u32* cursor  = (u32*)ws;     ws += 4 * (size_t)NBKT;    // init'd by k_scanB
    u32* part    = (u32*)ws;     ws += 4 * 256;
    u32* pay     = (u32*)ws;     ws += 4 * (size_t)N;
    int* cluster = (int*)ws;     ws += 4 * (size_t)N;

    const int nbN = (N + 255) / 256;
    // ===== PROBE: [memset,prep] pair ×3 (idempotent). Δ vs 198.5 = 2×(memset+prep) =====
    for (int rep = 0; rep < 3; ++rep) {
        hipMemsetAsync(hist, 0, sizeof(u32) * (NBKT + 2), stream);   // hist + flags
        k_prep<<<nbN, 256, 0, stream>>>(score, s, cluster, hist, ei, ntype, flags, N);
    }
    k_scanA<<<256, 256, 0, stream>>>(hist, part);
    k_scanB<<<256, 256, 0, stream>>>(hist, part, scan, cursor);
    k_scat<<<nbN, 256, 0, stream>>>(s, cursor, pack, N);
    k_rankperm<<<nbN, 256, 0, stream>>>(scan, pack, pay, s, ntype, &flags[1], cluster,
                                        out + o_nt, out + o_perm, out + o_vals, k, N);
    const int Dv = D / 4;
    const int gx = k * Dv;
    k_gx<<<(gx + 255) / 256, 256, 0, stream>>>(pay, s, (const f32x4*)x,
                                               (f32x4*)(out + o_xp), k, Dv, N);
    k_ea<<<2048, 256, 0, stream>>>(ei, &flags[0], elen, cluster,
                                   (const f32x4*)eattr,
                                   out + o_ei, out + o_elen, out + o_emask,
                                   (f32x4*)(out + o_eattr), E, N);
}

// Round 20
// 194.212 us; speedup vs baseline: 1.9995x; 1.5917x over previous
//
#include <hip/hip_runtime.h>
#include <math.h>

typedef unsigned int u32;
typedef unsigned long long u64;
typedef float f32x4 __attribute__((ext_vector_type(4)));

#define NDIG 2048          // 11-bit digits
#define TILE 256           // elements per multisplit tile (64 lanes x 4 rounds)
#define ROUNDS 4

// ===== Bit-exact replica of XLA's f32 tanh =====
__device__ __forceinline__ float xla_tanhf(float x) {
    float xc = fminf(fmaxf(x, -9.0f), 9.0f);
    float x2 = __fmul_rn(xc, xc);
    float p = -2.76076847742355e-16f;
    p = __fadd_rn(__fmul_rn(p, x2),  2.00018790482477e-13f);
    p = __fadd_rn(__fmul_rn(p, x2), -8.60467152213735e-11f);
    p = __fadd_rn(__fmul_rn(p, x2),  5.12229709037114e-08f);
    p = __fadd_rn(__fmul_rn(p, x2),  1.48572235717979e-05f);
    p = __fadd_rn(__fmul_rn(p, x2),  6.37261928875436e-04f);
    p = __fadd_rn(__fmul_rn(p, x2),  4.89352455891786e-03f);
    p = __fmul_rn(xc, p);
    float q = 1.19825839466702e-06f;
    q = __fadd_rn(__fmul_rn(q, x2),  1.18534705686654e-04f);
    q = __fadd_rn(__fmul_rn(q, x2),  2.26843463243900e-03f);
    q = __fadd_rn(__fmul_rn(q, x2),  4.89352518554385e-03f);
    float r = p / q;                     // IEEE f32 divide
    return (fabsf(x) < 0.0004f) ? x : r;
}

// ascending u32 order of key_desc(f) == DESCENDING float order of f (bijective)
__device__ __forceinline__ u32 key_desc(float f) {
    u32 u = __float_as_uint(f);
    u = (u & 0x80000000u) ? ~u : (u | 0x80000000u);
    return ~u;
}

__global__ void k_zf(u32* __restrict__ flags) {
    if (threadIdx.x < 2) flags[threadIdx.x] = 0u;
}

// keys+payload (coalesced), cluster init, int-width detect. NO ATOMIC HISTOGRAM.
__global__ void k_prep(const float* __restrict__ score, u64* __restrict__ pack0,
                       int* __restrict__ cluster,
                       const int* __restrict__ ei, const int* __restrict__ ntype,
                       u32* __restrict__ flags, int N) {
    int i = blockIdx.x * blockDim.x + threadIdx.x;
    if (i < 2048) { if (ei[2 * i + 1] != 0) atomicOr(&flags[0], 1u); }
    else if (i < 4096) { int j = i - 2048; if (ntype[2 * j + 1] != 0) atomicOr(&flags[1], 1u); }
    if (i < N) {
        float t = xla_tanhf(score[i]);
        cluster[i] = -1;
        pack0[i] = ((u64)key_desc(t) << 32) | (u32)i;
    }
}

// per-tile digit counts via wave ballot multisplit; writes [tile][digit] COALESCED
__global__ void k_count(const u64* __restrict__ src, u32* __restrict__ hist_td,
                        int shift, int N, int nT) {
    __shared__ u32 run[NDIG];
    const int tile = blockIdx.x;
    const int lane = threadIdx.x;           // block = 64 threads = 1 wave
    for (int r = lane; r < NDIG; r += 64) run[r] = 0u;
    __syncthreads();
    const int base = tile * TILE;
    for (int j = 0; j < ROUNDS; ++j) {
        int e = base + j * 64 + lane;
        if (e < N) {
            u32 key = (u32)(src[e] >> 32);
            u32 d = (key >> shift) & (NDIG - 1);
            u64 act = __ballot(1);
            u64 m = act;
            for (int b = 0; b < 11; ++b) {
                u64 bb = __ballot((d >> b) & 1);
                m &= ((d >> b) & 1) ? bb : ~bb;
            }
            int leader = __ffsll(m) - 1;
            if (lane == leader) run[d] += (u32)__popcll(m);
        }
        __syncthreads();
    }
    for (int r = lane; r < NDIG; r += 64)
        hist_td[(size_t)tile * NDIG + r] = run[r];
}

// LDS transpose [nT][NDIG] -> [NDIG][nT]; coalesced both sides
__global__ void k_tr(const u32* __restrict__ src, u32* __restrict__ dst, int nT) {
    __shared__ u32 sh[64][65];
    const int bt = blockIdx.x * 64;       // tile base
    const int bd = blockIdx.y * 64;       // digit base
    const int tx = threadIdx.x;           // 0..63
    for (int r = threadIdx.y; r < 64; r += blockDim.y) {
        int t = bt + r;
        sh[r][tx] = (t < nT) ? src[(size_t)t * NDIG + bd + tx] : 0u;
    }
    __syncthreads();
    for (int r = threadIdx.y; r < 64; r += blockDim.y) {
        int t = bt + tx;
        if (t < nT) dst[(size_t)(bd + r) * nT + t] = sh[tx][r];
    }
}

// reduce 256-entry chunks -> part[]
__global__ void k_red(const u32* __restrict__ h, u32* __restrict__ part) {
    __shared__ u32 sh[256];
    int b = blockIdx.x, t = threadIdx.x;
    sh[t] = h[(size_t)b * 256 + t];
    __syncthreads();
    for (int off = 128; off > 0; off >>= 1) {
        if (t < off) sh[t] += sh[t + off];
        __syncthreads();
    }
    if (t == 0) part[b] = sh[0];
}

// per-chunk: base = sum(part[0..b)) (strided), chunk exclusive scan IN PLACE
__global__ void k_scn(u32* __restrict__ h, const u32* __restrict__ part) {
    __shared__ u32 sh[256];
    __shared__ u32 base_sh;
    int b = blockIdx.x, t = threadIdx.x;
    u32 acc = 0;
    for (int j = t; j < b; j += 256) acc += part[j];
    sh[t] = acc;
    __syncthreads();
    for (int off = 128; off > 0; off >>= 1) {
        if (t < off) sh[t] += sh[t + off];
        __syncthreads();
    }
    if (t == 0) base_sh = sh[0];
    __syncthreads();
    u32 base = base_sh;
    u32 v = h[(size_t)b * 256 + t];
    sh[t] = v;
    __syncthreads();
    for (int off = 1; off < 256; off <<= 1) {
        u32 x = sh[t];
        u32 y = (t >= off) ? sh[t - off] : 0u;
        __syncthreads();
        sh[t] = x + y;
        __syncthreads();
    }
    h[(size_t)b * 256 + t] = base + sh[t] - v;   // exclusive prefix
}

// stable scatter: pos = scanned[digit][tile] + in-tile stable rank (ballot)
__global__ void k_scatR(const u64* __restrict__ src, u64* __restrict__ dst,
                        const u32* __restrict__ scn, int shift, int N, int nT) {
    __shared__ u32 run[NDIG];
    const int tile = blockIdx.x;
    const int lane = threadIdx.x;
    for (int r = lane; r < NDIG; r += 64) run[r] = 0u;
    __syncthreads();
    const int base = tile * TILE;
    for (int j = 0; j < ROUNDS; ++j) {
        int e = base + j * 64 + lane;
        if (e < N) {
            u64 v = src[e];
            u32 key = (u32)(v >> 32);
            u32 d = (key >> shift) & (NDIG - 1);
            u64 act = __ballot(1);
            u64 m = act;
            for (int b = 0; b < 11; ++b) {
                u64 bb = __ballot((d >> b) & 1);
                m &= ((d >> b) & 1) ? bb : ~bb;
            }
            u32 wrank = (u32)__popcll(m & ((1ull << lane) - 1ull));
            u32 old = run[d];                      // all lanes read pre-round count
            u32 pos = scn[(size_t)d * nT + tile] + old + wrank;
            int leader = __ffsll(m) - 1;
            if (lane == leader) run[d] = old + (u32)__popcll(m);
            if (pos < (u32)N) dst[pos] = v;
        }
        __syncthreads();
    }
}

// fix low-10-bit/idx order within same-top22 runs (tiny, contiguous) + emit perm outputs
__global__ void k_pfix(const u64* __restrict__ srt, u64* __restrict__ pay64,
                       int* __restrict__ cluster,
                       const int* __restrict__ ntype, const u32* __restrict__ ntFlag,
                       float* __restrict__ o_nt, float* __restrict__ o_perm,
                       float* __restrict__ o_vals, int k, int N) {
    int r = blockIdx.x * blockDim.x + threadIdx.x;
    if (r >= N) return;
    u64 pk = srt[r];
    u64 t22 = pk >> 42;
    int rs = r;
    while (rs > 0 && (r - rs) < 4096 && (srt[rs - 1] >> 42) == t22) --rs;
    int rf = rs;
    for (int j = rs; j < N && (j - rs) < 8192; ++j) {
        u64 q = srt[j];
        if ((q >> 42) != t22) break;
        rf += (q < pk);                  // full (key,idx) lexicographic order
    }
    if (rf < k) {
        u32 ip = (u32)pk;
        if (ip >= (u32)N) ip = 0;        // defensive
        u32 kb = (u32)(pk >> 32);
        u32 up = ~kb;                    // invert key_desc: recover tanh bits exactly
        u32 tb = (up >> 31) ? (up & 0x7FFFFFFFu) : ~up;
        pay64[rf] = ((u64)tb << 32) | ip;
        cluster[ip] = rf;
        o_perm[rf] = (float)ip;
        o_vals[rf] = __uint_as_float(tb);
        int nt = (*ntFlag == 0u) ? ntype[2 * (size_t)ip] : ntype[ip];
        o_nt[rf] = (float)nt;
    }
}

// x-gather: (val,idx) packed in pay64; regular loads, NT store
__global__ void k_gx(const u64* __restrict__ pay64,
                     const f32x4* __restrict__ x4, f32x4* __restrict__ out4,
                     int k, int Dv, int N) {
    int idx = blockIdx.x * blockDim.x + threadIdx.x;
    if (idx < k * Dv) {
        int r = idx / Dv, c = idx - r * Dv;
        u64 pv = pay64[r];
        u32 p = (u32)pv;
        float v = __uint_as_float((u32)(pv >> 32));
        if (p >= (u32)N) { p = 0; v = 0.0f; }   // defensive
        f32x4 a = x4[(size_t)p * Dv + c];
        a = a * v;
        __builtin_nontemporal_store(a, out4 + idx);
    }
}

// WAVE-chunked fused edges+attr (R16-proven)
__global__ void k_ea(const int* __restrict__ ei, const u32* __restrict__ eiFlag,
                     const float* __restrict__ elen, const int* __restrict__ cluster,
                     const f32x4* __restrict__ attr4,
                     float* __restrict__ o_ei, float* __restrict__ o_len,
                     float* __restrict__ o_mask, f32x4* __restrict__ o_attr4,
                     int E, int N) {
    const bool w64 = (*eiFlag == 0u);
    const int lane = threadIdx.x & 63;
    const int waveId = (blockIdx.x * blockDim.x + threadIdx.x) >> 6;
    const int nWaves = (gridDim.x * blockDim.x) >> 6;
    const int nChunk = (E + 63) >> 6;
    for (int ch = waveId; ch < nChunk; ch += nWaves) {
        int e = ch * 64 + lane;
        int mfl = 0;
        if (e < E) {
            int a, b;
            if (w64) { a = ei[2 * (size_t)e]; b = ei[2 * ((size_t)E + (size_t)e)]; }
            else { a = ei[e]; b = ei[(size_t)E + e]; }
            bool ok = ((u32)a < (u32)N) && ((u32)b < (u32)N);
            int r  = ok ? cluster[a] : -1;
            int cc = ok ? cluster[b] : -1;
            bool m = (r >= 0) && (cc >= 0);
            mfl = m ? 1 : 0;
            __builtin_nontemporal_store(m ? (float)r  : 0.0f, o_ei + e);
            __builtin_nontemporal_store(m ? (float)cc : 0.0f, o_ei + (size_t)E + e);
            __builtin_nontemporal_store(m ? elen[e] : 0.0f, o_len + e);
            __builtin_nontemporal_store(m ? 1.0f : 0.0f, o_mask + e);
        }
        long long base4 = (long long)ch * 256;
        #pragma unroll
        for (int j = 0; j < 4; ++j) {
            long long idx4 = base4 + j * 64 + lane;
            int owner = j * 16 + (lane >> 2);
            int m = __shfl(mfl, owner);
            int ee = ch * 64 + owner;
            if (ee < E) {
                f32x4 v = {0.f, 0.f, 0.f, 0.f};
                if (m) v = attr4[idx4];
                __builtin_nontemporal_store(v, o_attr4 + idx4);
            }
        }
    }
}

extern "C" void kernel_launch(void* const* d_in, const int* in_sizes, int n_in,
                              void* d_out, int out_size, void* d_ws, size_t ws_size,
                              hipStream_t stream) {
    const float* x     = (const float*)d_in[0];
    const float* score = (const float*)d_in[1];
    const int*   ei    = (const int*)d_in[2];
    const float* eattr = (const float*)d_in[3];
    const int*   ntype = (const int*)d_in[4];
    const float* elen  = (const float*)d_in[5];

    const int N  = in_sizes[1];
    const int D  = in_sizes[0] / N;
    const int E  = in_sizes[5];
    const int DE = in_sizes[3] / E;
    const int k  = (N + 1) / 2;     // ceil(0.5 * N)

    // d_out is FLOAT32. RETURN-ORDER layout:
    // x_p | edge_index | edge_attr_p | node_type | perm | vals | edge_lengths | edge_mask
    float* out = (float*)d_out;
    const size_t o_xp    = 0;
    const size_t o_ei    = o_xp    + (size_t)k * D;
    const size_t o_eattr = o_ei    + 2 * (size_t)E;
    const size_t o_nt    = o_eattr + (size_t)E * DE;
    const size_t o_perm  = o_nt    + (size_t)k;
    const size_t o_vals  = o_perm  + (size_t)k;
    const size_t o_elen  = o_vals  + (size_t)k;
    const size_t o_emask = o_elen  + (size_t)E;

    const int nT = (N + TILE - 1) / TILE;              // 391
    const int histN = NDIG * nT;                       // 800768
    const int nChunk = (histN + 255) / 256;            // 3128 (exact)

    char* ws = (char*)d_ws;
    u64* pack0   = (u64*)ws;     ws += 8 * (size_t)N;
    u64* pack1   = (u64*)ws;     ws += 8 * (size_t)N;
    u64* pay64   = (u64*)ws;     ws += 8 * (size_t)N;
    u32* hist_td = (u32*)ws;     ws += 4 * (size_t)histN;
    u32* hist_dt = (u32*)ws;     ws += 4 * (size_t)histN;
    u32* part    = (u32*)ws;     ws += 4 * (size_t)nChunk;
    u32* flags   = (u32*)ws;     ws += 4 * 2;
    int* cluster = (int*)ws;     ws += 4 * (size_t)N;

    const int nbN = (N + 255) / 256;
    const dim3 trGrid((nT + 63) / 64, NDIG / 64);
    const dim3 trBlk(64, 4);

    k_zf<<<1, 64, 0, stream>>>(flags);
    k_prep<<<nbN, 256, 0, stream>>>(score, pack0, cluster, ei, ntype, flags, N);

    // pass A: bits [10,21)
    k_count<<<nT, 64, 0, stream>>>(pack0, hist_td, 10, N, nT);
    k_tr<<<trGrid, trBlk, 0, stream>>>(hist_td, hist_dt, nT);
    k_red<<<nChunk, 256, 0, stream>>>(hist_dt, part);
    k_scn<<<nChunk, 256, 0, stream>>>(hist_dt, part);
    k_scatR<<<nT, 64, 0, stream>>>(pack0, pack1, hist_dt, 10, N, nT);

    // pass B: bits [21,32)
    k_count<<<nT, 64, 0, stream>>>(pack1, hist_td, 21, N, nT);
    k_tr<<<trGrid, trBlk, 0, stream>>>(hist_td, hist_dt, nT);
    k_red<<<nChunk, 256, 0, stream>>>(hist_dt, part);
    k_scn<<<nChunk, 256, 0, stream>>>(hist_dt, part);
    k_scatR<<<nT, 64, 0, stream>>>(pack1, pack0, hist_dt, 21, N, nT);
    // pack0 now sorted by key bits [10,32), stable (idx-ascending within equal)

    k_pfix<<<nbN, 256, 0, stream>>>(pack0, pay64, cluster, ntype, &flags[1],
                                    out + o_nt, out + o_perm, out + o_vals, k, N);

    const int Dv = D / 4;
    const int gx = k * Dv;
    k_gx<<<(gx + 255) / 256, 256, 0, stream>>>(pay64, (const f32x4*)x,
                                               (f32x4*)(out + o_xp), k, Dv, N);
    k_ea<<<2048, 256, 0, stream>>>(ei, &flags[0], elen, cluster,
                                   (const f32x4*)eattr,
                                   out + o_ei, out + o_elen, out + o_emask,
                                   (f32x4*)(out + o_eattr), E, N);
}

// Round 21
// 135.482 us; speedup vs baseline: 2.8662x; 1.4335x over previous
//
#include <hip/hip_runtime.h>
#include <math.h>

typedef unsigned int u32;
typedef unsigned long long u64;
typedef float f32x4 __attribute__((ext_vector_type(4)));

#define NDIG 2048          // 11-bit digits
#define TILE 256           // elements per multisplit tile (64 lanes x 4 rounds)
#define ROUNDS 4

// ===== Bit-exact replica of XLA's f32 tanh =====
__device__ __forceinline__ float xla_tanhf(float x) {
    float xc = fminf(fmaxf(x, -9.0f), 9.0f);
    float x2 = __fmul_rn(xc, xc);
    float p = -2.76076847742355e-16f;
    p = __fadd_rn(__fmul_rn(p, x2),  2.00018790482477e-13f);
    p = __fadd_rn(__fmul_rn(p, x2), -8.60467152213735e-11f);
    p = __fadd_rn(__fmul_rn(p, x2),  5.12229709037114e-08f);
    p = __fadd_rn(__fmul_rn(p, x2),  1.48572235717979e-05f);
    p = __fadd_rn(__fmul_rn(p, x2),  6.37261928875436e-04f);
    p = __fadd_rn(__fmul_rn(p, x2),  4.89352455891786e-03f);
    p = __fmul_rn(xc, p);
    float q = 1.19825839466702e-06f;
    q = __fadd_rn(__fmul_rn(q, x2),  1.18534705686654e-04f);
    q = __fadd_rn(__fmul_rn(q, x2),  2.26843463243900e-03f);
    q = __fadd_rn(__fmul_rn(q, x2),  4.89352518554385e-03f);
    float r = p / q;                     // IEEE f32 divide
    return (fabsf(x) < 0.0004f) ? x : r;
}

// ascending u32 order of key_desc(f) == DESCENDING float order of f (bijective)
__device__ __forceinline__ u32 key_desc(float f) {
    u32 u = __float_as_uint(f);
    u = (u & 0x80000000u) ? ~u : (u | 0x80000000u);
    return ~u;
}

// PASS-A count FUSED with prep (tanh+pack+cluster) and atomic-free detect.
// Block 0 wave-ballots the int64/int32 layout flags (no pre-zero needed).
// hist written DIGIT-MAJOR directly (k_tr eliminated).
__global__ void k_countP(const float* __restrict__ score, u64* __restrict__ pack0,
                         int* __restrict__ cluster,
                         const int* __restrict__ ei, const int* __restrict__ ntype,
                         u32* __restrict__ flags, u32* __restrict__ hist_dt,
                         int N, int nT) {
    __shared__ u32 run[NDIG];
    const int tile = blockIdx.x;
    const int lane = threadIdx.x;           // 64 threads = 1 wave
    if (tile == 0) {
        int v1 = ei[2 * lane + 1];          // odd words: 0 iff int64 little-endian
        u64 b1 = __ballot(v1 != 0);
        int v2 = ntype[2 * lane + 1];
        u64 b2 = __ballot(v2 != 0);
        if (lane == 0) { flags[0] = (b1 != 0ull) ? 1u : 0u;
                         flags[1] = (b2 != 0ull) ? 1u : 0u; }
    }
    for (int r = lane; r < NDIG; r += 64) run[r] = 0u;
    __syncthreads();
    const int base = tile * TILE;
    for (int j = 0; j < ROUNDS; ++j) {
        int e = base + j * 64 + lane;
        if (e < N) {
            float t = xla_tanhf(score[e]);
            cluster[e] = -1;
            u32 key = key_desc(t);
            pack0[e] = ((u64)key << 32) | (u32)e;
            u32 d = (key >> 10) & (NDIG - 1);
            u64 m = __ballot(1);
            for (int b = 0; b < 11; ++b) {
                u64 bb = __ballot((d >> b) & 1);
                m &= ((d >> b) & 1) ? bb : ~bb;
            }
            int leader = __ffsll(m) - 1;
            if (lane == leader) run[d] += (u32)__popcll(m);
        }
        __syncthreads();
    }
    for (int r = lane; r < NDIG; r += 64)
        hist_dt[(size_t)r * nT + tile] = run[r];       // digit-major
}

// PASS-B count (reads packed keys), digit-major writes
__global__ void k_count(const u64* __restrict__ src, u32* __restrict__ hist_dt,
                        int shift, int N, int nT) {
    __shared__ u32 run[NDIG];
    const int tile = blockIdx.x;
    const int lane = threadIdx.x;
    for (int r = lane; r < NDIG; r += 64) run[r] = 0u;
    __syncthreads();
    const int base = tile * TILE;
    for (int j = 0; j < ROUNDS; ++j) {
        int e = base + j * 64 + lane;
        if (e < N) {
            u32 key = (u32)(src[e] >> 32);
            u32 d = (key >> shift) & (NDIG - 1);
            u64 m = __ballot(1);
            for (int b = 0; b < 11; ++b) {
                u64 bb = __ballot((d >> b) & 1);
                m &= ((d >> b) & 1) ? bb : ~bb;
            }
            int leader = __ffsll(m) - 1;
            if (lane == leader) run[d] += (u32)__popcll(m);
        }
        __syncthreads();
    }
    for (int r = lane; r < NDIG; r += 64)
        hist_dt[(size_t)r * nT + tile] = run[r];
}

// reduce 256-entry chunks -> part[]  (R20-proven)
__global__ void k_red(const u32* __restrict__ h, u32* __restrict__ part) {
    __shared__ u32 sh[256];
    int b = blockIdx.x, t = threadIdx.x;
    sh[t] = h[(size_t)b * 256 + t];
    __syncthreads();
    for (int off = 128; off > 0; off >>= 1) {
        if (t < off) sh[t] += sh[t + off];
        __syncthreads();
    }
    if (t == 0) part[b] = sh[0];
}

// per-chunk: base = sum(part[0..b)) (strided), chunk exclusive scan IN PLACE  (R20-proven)
__global__ void k_scn(u32* __restrict__ h, const u32* __restrict__ part) {
    __shared__ u32 sh[256];
    __shared__ u32 base_sh;
    int b = blockIdx.x, t = threadIdx.x;
    u32 acc = 0;
    for (int j = t; j < b; j += 256) acc += part[j];
    sh[t] = acc;
    __syncthreads();
    for (int off = 128; off > 0; off >>= 1) {
        if (t < off) sh[t] += sh[t + off];
        __syncthreads();
    }
    if (t == 0) base_sh = sh[0];
    __syncthreads();
    u32 base = base_sh;
    u32 v = h[(size_t)b * 256 + t];
    sh[t] = v;
    __syncthreads();
    for (int off = 1; off < 256; off <<= 1) {
        u32 x = sh[t];
        u32 y = (t >= off) ? sh[t - off] : 0u;
        __syncthreads();
        sh[t] = x + y;
        __syncthreads();
    }
    h[(size_t)b * 256 + t] = base + sh[t] - v;   // exclusive prefix
}

// stable scatter: pos = scanned[digit][tile] + in-tile stable rank  (R20-proven)
__global__ void k_scatR(const u64* __restrict__ src, u64* __restrict__ dst,
                        const u32* __restrict__ scn, int shift, int N, int nT) {
    __shared__ u32 run[NDIG];
    const int tile = blockIdx.x;
    const int lane = threadIdx.x;
    for (int r = lane; r < NDIG; r += 64) run[r] = 0u;
    __syncthreads();
    const int base = tile * TILE;
    for (int j = 0; j < ROUNDS; ++j) {
        int e = base + j * 64 + lane;
        if (e < N) {
            u64 v = src[e];
            u32 key = (u32)(v >> 32);
            u32 d = (key >> shift) & (NDIG - 1);
            u64 m = __ballot(1);
            for (int b = 0; b < 11; ++b) {
                u64 bb = __ballot((d >> b) & 1);
                m &= ((d >> b) & 1) ? bb : ~bb;
            }
            u32 wrank = (u32)__popcll(m & ((1ull << lane) - 1ull));
            u32 old = run[d];
            u32 pos = scn[(size_t)d * nT + tile] + old + wrank;
            int leader = __ffsll(m) - 1;
            if (lane == leader) run[d] = old + (u32)__popcll(m);
            if (pos < (u32)N) dst[pos] = v;
        }
        __syncthreads();
    }
}

// fix low-10-bit/idx order within same-top22 runs + emit perm outputs  (R20-proven)
__global__ void k_pfix(const u64* __restrict__ srt, u64* __restrict__ pay64,
                       int* __restrict__ cluster,
                       const int* __restrict__ ntype, const u32* __restrict__ ntFlag,
                       float* __restrict__ o_nt, float* __restrict__ o_perm,
                       float* __restrict__ o_vals, int k, int N) {
    int r = blockIdx.x * blockDim.x + threadIdx.x;
    if (r >= N) return;
    u64 pk = srt[r];
    u64 t22 = pk >> 42;
    int rs = r;
    while (rs > 0 && (r - rs) < 4096 && (srt[rs - 1] >> 42) == t22) --rs;
    int rf = rs;
    for (int j = rs; j < N && (j - rs) < 8192; ++j) {
        u64 q = srt[j];
        if ((q >> 42) != t22) break;
        rf += (q < pk);                  // full (key,idx) lexicographic order
    }
    if (rf < k) {
        u32 ip = (u32)pk;
        if (ip >= (u32)N) ip = 0;        // defensive
        u32 kb = (u32)(pk >> 32);
        u32 up = ~kb;                    // invert key_desc: recover tanh bits exactly
        u32 tb = (up >> 31) ? (up & 0x7FFFFFFFu) : ~up;
        pay64[rf] = ((u64)tb << 32) | ip;
        cluster[ip] = rf;
        o_perm[rf] = (float)ip;
        o_vals[rf] = __uint_as_float(tb);
        int nt = (*ntFlag == 0u) ? ntype[2 * (size_t)ip] : ntype[ip];
        o_nt[rf] = (float)nt;
    }
}

// x-gather: (val,idx) packed in pay64; regular loads, NT store  (R20-proven)
__global__ void k_gx(const u64* __restrict__ pay64,
                     const f32x4* __restrict__ x4, f32x4* __restrict__ out4,
                     int k, int Dv, int N) {
    int idx = blockIdx.x * blockDim.x + threadIdx.x;
    if (idx < k * Dv) {
        int r = idx / Dv, c = idx - r * Dv;
        u64 pv = pay64[r];
        u32 p = (u32)pv;
        float v = __uint_as_float((u32)(pv >> 32));
        if (p >= (u32)N) { p = 0; v = 0.0f; }   // defensive
        f32x4 a = x4[(size_t)p * Dv + c];
        a = a * v;
        __builtin_nontemporal_store(a, out4 + idx);
    }
}

// WAVE-chunked fused edges+attr (R16-proven)
__global__ void k_ea(const int* __restrict__ ei, const u32* __restrict__ eiFlag,
                     const float* __restrict__ elen, const int* __restrict__ cluster,
                     const f32x4* __restrict__ attr4,
                     float* __restrict__ o_ei, float* __restrict__ o_len,
                     float* __restrict__ o_mask, f32x4* __restrict__ o_attr4,
                     int E, int N) {
    const bool w64 = (*eiFlag == 0u);
    const int lane = threadIdx.x & 63;
    const int waveId = (blockIdx.x * blockDim.x + threadIdx.x) >> 6;
    const int nWaves = (gridDim.x * blockDim.x) >> 6;
    const int nChunk = (E + 63) >> 6;
    for (int ch = waveId; ch < nChunk; ch += nWaves) {
        int e = ch * 64 + lane;
        int mfl = 0;
        if (e < E) {
            int a, b;
            if (w64) { a = ei[2 * (size_t)e]; b = ei[2 * ((size_t)E + (size_t)e)]; }
            else { a = ei[e]; b = ei[(size_t)E + e]; }
            bool ok = ((u32)a < (u32)N) && ((u32)b < (u32)N);
            int r  = ok ? cluster[a] : -1;
            int cc = ok ? cluster[b] : -1;
            bool m = (r >= 0) && (cc >= 0);
            mfl = m ? 1 : 0;
            __builtin_nontemporal_store(m ? (float)r  : 0.0f, o_ei + e);
            __builtin_nontemporal_store(m ? (float)cc : 0.0f, o_ei + (size_t)E + e);
            __builtin_nontemporal_store(m ? elen[e] : 0.0f, o_len + e);
            __builtin_nontemporal_store(m ? 1.0f : 0.0f, o_mask + e);
        }
        long long base4 = (long long)ch * 256;
        #pragma unroll
        for (int j = 0; j < 4; ++j) {
            long long idx4 = base4 + j * 64 + lane;
            int owner = j * 16 + (lane >> 2);
            int m = __shfl(mfl, owner);
            int ee = ch * 64 + owner;
            if (ee < E) {
                f32x4 v = {0.f, 0.f, 0.f, 0.f};
                if (m) v = attr4[idx4];
                __builtin_nontemporal_store(v, o_attr4 + idx4);
            }
        }
    }
}

extern "C" void kernel_launch(void* const* d_in, const int* in_sizes, int n_in,
                              void* d_out, int out_size, void* d_ws, size_t ws_size,
                              hipStream_t stream) {
    const float* x     = (const float*)d_in[0];
    const float* score = (const float*)d_in[1];
    const int*   ei    = (const int*)d_in[2];
    const float* eattr = (const float*)d_in[3];
    const int*   ntype = (const int*)d_in[4];
    const float* elen  = (const float*)d_in[5];

    const int N  = in_sizes[1];
    const int D  = in_sizes[0] / N;
    const int E  = in_sizes[5];
    const int DE = in_sizes[3] / E;
    const int k  = (N + 1) / 2;     // ceil(0.5 * N)

    // d_out is FLOAT32. RETURN-ORDER layout:
    // x_p | edge_index | edge_attr_p | node_type | perm | vals | edge_lengths | edge_mask
    float* out = (float*)d_out;
    const size_t o_xp    = 0;
    const size_t o_ei    = o_xp    + (size_t)k * D;
    const size_t o_eattr = o_ei    + 2 * (size_t)E;
    const size_t o_nt    = o_eattr + (size_t)E * DE;
    const size_t o_perm  = o_nt    + (size_t)k;
    const size_t o_vals  = o_perm  + (size_t)k;
    const size_t o_elen  = o_vals  + (size_t)k;
    const size_t o_emask = o_elen  + (size_t)E;

    const int nT = (N + TILE - 1) / TILE;              // 391
    const int histN = NDIG * nT;                       // 800768
    const int nChunk = (histN + 255) / 256;            // 3128 (exact)

    char* ws = (char*)d_ws;
    u64* pack0   = (u64*)ws;     ws += 8 * (size_t)N;
    u64* pack1   = (u64*)ws;     ws += 8 * (size_t)N;
    u64* pay64   = (u64*)ws;     ws += 8 * (size_t)N;
    u32* hist_dt = (u32*)ws;     ws += 4 * (size_t)histN;
    u32* part    = (u32*)ws;     ws += 4 * (size_t)nChunk;
    u32* flags   = (u32*)ws;     ws += 4 * 2;
    int* cluster = (int*)ws;     ws += 4 * (size_t)N;

    const int nbN = (N + 255) / 256;

    // pass A: bits [10,21)  (count fused with prep+detect)
    k_countP<<<nT, 64, 0, stream>>>(score, pack0, cluster, ei, ntype, flags,
                                    hist_dt, N, nT);
    k_red<<<nChunk, 256, 0, stream>>>(hist_dt, part);
    k_scn<<<nChunk, 256, 0, stream>>>(hist_dt, part);
    k_scatR<<<nT, 64, 0, stream>>>(pack0, pack1, hist_dt, 10, N, nT);

    // pass B: bits [21,32)
    k_count<<<nT, 64, 0, stream>>>(pack1, hist_dt, 21, N, nT);
    k_red<<<nChunk, 256, 0, stream>>>(hist_dt, part);
    k_scn<<<nChunk, 256, 0, stream>>>(hist_dt, part);
    k_scatR<<<nT, 64, 0, stream>>>(pack1, pack0, hist_dt, 21, N, nT);
    // pack0 now sorted by key bits [10,32), stable (idx-ascending within equal)

    k_pfix<<<nbN, 256, 0, stream>>>(pack0, pay64, cluster, ntype, &flags[1],
                                    out + o_nt, out + o_perm, out + o_vals, k, N);

    const int Dv = D / 4;
    const int gx = k * Dv;
    k_gx<<<(gx + 255) / 256, 256, 0, stream>>>(pay64, (const f32x4*)x,
                                               (f32x4*)(out + o_xp), k, Dv, N);
    k_ea<<<2048, 256, 0, stream>>>(ei, &flags[0], elen, cluster,
                                   (const f32x4*)eattr,
                                   out + o_ei, out + o_elen, out + o_emask,
                                   (f32x4*)(out + o_eattr), E, N);
}